// Round 22
// baseline (57.128 us; speedup 1.0000x reference)
//
#include <hip/hip_runtime.h>
#include <cstdint>
#include <cstddef>

#define TT  2048
#define HH  1024
#define FFN 2048
#define NL  4
#define BK  64
#define BM  256
#define SK2 2            // gemm2 split-K (chunk = 1024 -> NT=16)

typedef __attribute__((ext_vector_type(8))) short bf16x8;
typedef __attribute__((ext_vector_type(4))) unsigned short u16x4;
typedef __attribute__((ext_vector_type(4))) float f32x4;

__device__ __forceinline__ unsigned short f2bf(float f) {
  unsigned u = __builtin_bit_cast(unsigned, f);
  u += 0x7FFFu + ((u >> 16) & 1u);           // RNE
  return (unsigned short)(u >> 16);
}

__device__ __forceinline__ bf16x8 pack8(f32x4 f0, f32x4 f1) {
  bf16x8 v;
  v[0] = (short)f2bf(f0[0]); v[1] = (short)f2bf(f0[1]);
  v[2] = (short)f2bf(f0[2]); v[3] = (short)f2bf(f0[3]);
  v[4] = (short)f2bf(f1[0]); v[5] = (short)f2bf(f1[1]);
  v[6] = (short)f2bf(f1[2]); v[7] = (short)f2bf(f1[3]);
  return v;
}

__device__ __forceinline__ u16x4 pack4(f32x4 f) {
  u16x4 v;
  v[0] = f2bf(f[0]); v[1] = f2bf(f[1]); v[2] = f2bf(f[2]); v[3] = f2bf(f[3]);
  return v;
}

__device__ __forceinline__ void async16(void* lds, const void* g) {
  __builtin_amdgcn_global_load_lds(
      (const __attribute__((address_space(1))) unsigned int*)g,
      (__attribute__((address_space(3))) unsigned int*)lds, 16, 0, 0);
}

// XOR swizzle inside [rows][64 bf16] (128 B rows); involution (rule 21).
__device__ __forceinline__ int swz(int b) { return b ^ (((b >> 7) & 7) << 4); }

// lgkm-only drain + raw barrier: counted global loads stay in flight (T4).
__device__ __forceinline__ void lds_barrier() {
  asm volatile("s_waitcnt lgkmcnt(0)" ::: "memory");
  __builtin_amdgcn_s_barrier();
}

// ---------------------------------------------------------------- zero + build (fused)
__global__ __launch_bounds__(256) void k_zb(
    float* __restrict__ out, const int* __restrict__ sel,
    const float* __restrict__ rw, int* __restrict__ cnt,
    int* __restrict__ tok, float* __restrict__ wgt) {
  int b = blockIdx.x;
  if (b < 2048) {
    f32x4 z = {0.f, 0.f, 0.f, 0.f};
    reinterpret_cast<f32x4*>(out + (size_t)b * HH)[threadIdx.x] = z;
    return;
  }
  // build block (single block, LDS-atomic compaction)
  __shared__ int lcnt[NL];
  int tid = threadIdx.x;
  if (tid < NL) lcnt[tid] = 0;
  __syncthreads();
#pragma unroll
  for (int r = 0; r < TT / 256; ++r) {
    int t = r * 256 + tid;
    int   s0 = sel[t*4+0], s1 = sel[t*4+1], s2 = sel[t*4+2], s3 = sel[t*4+3];
    float r0 = rw[t*4+0],  r1 = rw[t*4+1],  r2 = rw[t*4+2],  r3 = rw[t*4+3];
#pragma unroll
    for (int i = 0; i < NL; ++i) {
      int eid = i * 8;
      float w = 0.f; bool m = false;
      if (s0 == eid) { w += r0; m = true; }
      if (s1 == eid) { w += r1; m = true; }
      if (s2 == eid) { w += r2; m = true; }
      if (s3 == eid) { w += r3; m = true; }
      if (m) {
        int p = atomicAdd(&lcnt[i], 1);
        tok[i*TT + p] = t;
        wgt[i*TT + p] = w;
      }
    }
  }
  __syncthreads();
  if (tid < NL) cnt[tid] = lcnt[tid];
}

// ---------------------------------------------------------------- gather
__global__ void k_gather(const float* __restrict__ hidden, const int* __restrict__ cnt,
                         const int* __restrict__ tok, unsigned short* __restrict__ X) {
  int p = blockIdx.x, e = blockIdx.y;
  if (p >= cnt[e]) return;
  int t = tok[e*TT + p];
  const f32x4* src = reinterpret_cast<const f32x4*>(hidden + (size_t)t * HH);
  f32x4 a = src[threadIdx.x*2], b = src[threadIdx.x*2 + 1];
  reinterpret_cast<bf16x8*>(X + ((size_t)e*TT + p) * HH)[threadIdx.x] = pack8(a, b);
}

// ---------------------------------------------------------------- GEMM1
// R13 pipeline (D=3 / 4-slot ring) + T5 setprio around MFMA cluster.
__global__ __launch_bounds__(512) void k_gemm1(
    const unsigned short* __restrict__ X, const float* __restrict__ gup,
    const int* __restrict__ cnt, unsigned short* __restrict__ Hb) {
  int bid = blockIdx.x;
  int xcd = bid & 7;
  int e   = xcd >> 1;
  int idx = (bid >> 3) * 2 + (xcd & 1);   // 0..63
  int n0  = idx * 32;
  int c   = cnt[e];

  __shared__ alignas(16) unsigned short As[4][BM*BK];   // 4 x 32 KB
  __shared__ alignas(16) unsigned short Bs[2][64*BK];   // 2 x 8 KB

  int tid  = threadIdx.x;
  int lane = tid & 63, wv = tid >> 6;     // 8 waves
  int lr = lane & 15,  lk = lane >> 4;
  int wm = wv >> 1,    wn = wv & 1;       // 4M x 2N

  const unsigned short* Ab = X   + (size_t)e * TT * HH;
  const float*          Gb = gup + (size_t)e * 2 * FFN * HH;

  int arow[4], acol[4], dstA[4];
#pragma unroll
  for (int cc = 0; cc < 4; ++cc) {
    int chunk = wv * 4 + cc;
    int P = chunk * 1024 + lane * 16;
    arow[cc] = P >> 7;
    acol[cc] = (P & 127) ^ ((arow[cc] & 7) << 4);
    dstA[cc] = P;
  }

  int rb  = tid >> 3;                     // 0..63
  int cbf = (tid & 7) * 8;
  int grow = (rb < 32) ? (n0 + rb) : (FFN + n0 + rb - 32);
  const float* gB = Gb + (size_t)grow * HH + cbf;
  int wb = swz(rb * 128 + cbf * 2);

  int aoff[4][2], bgo[2], buo[2];
#pragma unroll
  for (int mi = 0; mi < 4; ++mi)
#pragma unroll
    for (int kk = 0; kk < 2; ++kk)
      aoff[mi][kk] = swz((wm*64 + mi*16 + lr) * 128 + kk*64 + lk*16);
#pragma unroll
  for (int kk = 0; kk < 2; ++kk) {
    bgo[kk] = swz((wn*16 + lr) * 128 + kk*64 + lk*16);
    buo[kk] = swz((32 + wn*16 + lr) * 128 + kk*64 + lk*16);
  }

  const int NT = HH / BK;   // 16

  for (int m0 = 0; m0 < c; m0 += BM) {
    __syncthreads();

    const char* srcA[4];
#pragma unroll
    for (int cc = 0; cc < 4; ++cc)
      srcA[cc] = (const char*)(Ab + (size_t)(m0 + arow[cc]) * HH) + acol[cc];

    f32x4 accg[4], accu[4];
    f32x4 z = {0.f, 0.f, 0.f, 0.f};
#pragma unroll
    for (int a = 0; a < 4; ++a) { accg[a] = z; accu[a] = z; }

    f32x4 br[3][2];

    br[0][0] = *(const f32x4*)(gB);
    br[0][1] = *(const f32x4*)(gB + 4);
#pragma unroll
    for (int cc = 0; cc < 4; ++cc) async16((char*)As[0] + dstA[cc], srcA[cc]);
#pragma unroll
    for (int cc = 0; cc < 4; ++cc) async16((char*)As[1] + dstA[cc], srcA[cc] + BK*2);
#pragma unroll
    for (int cc = 0; cc < 4; ++cc) async16((char*)As[2] + dstA[cc], srcA[cc] + 2*BK*2);
    br[1][0] = *(const f32x4*)(gB + BK);
    br[1][1] = *(const f32x4*)(gB + BK + 4);
    br[2][0] = *(const f32x4*)(gB + 2*BK);
    br[2][1] = *(const f32x4*)(gB + 2*BK + 4);
    *(bf16x8*)((char*)Bs[0] + wb) = pack8(br[0][0], br[0][1]);
    asm volatile("s_waitcnt vmcnt(12)" ::: "memory");
    lds_barrier();

#pragma unroll
    for (int t = 0; t < NT; ++t) {
      if (t + 3 < NT) {
        int k3 = (t + 3) * BK;
#pragma unroll
        for (int cc = 0; cc < 4; ++cc)
          async16((char*)As[(t+3) & 3] + dstA[cc], srcA[cc] + k3*2);
        br[(t+3) % 3][0] = *(const f32x4*)(gB + k3);
        br[(t+3) % 3][1] = *(const f32x4*)(gB + k3 + 4);
      }
      __builtin_amdgcn_sched_barrier(0);
      {
        const char* Asc = (const char*)As[t & 3];
        const char* Bsc = (const char*)Bs[t & 1];
        __builtin_amdgcn_s_setprio(1);
#pragma unroll
        for (int kk = 0; kk < 2; ++kk) {
          bf16x8 bg = *(const bf16x8*)(Bsc + bgo[kk]);
          bf16x8 bu = *(const bf16x8*)(Bsc + buo[kk]);
#pragma unroll
          for (int mi = 0; mi < 4; ++mi) {
            bf16x8 a = *(const bf16x8*)(Asc + aoff[mi][kk]);
            accg[mi] = __builtin_amdgcn_mfma_f32_16x16x32_bf16(a, bg, accg[mi], 0, 0, 0);
            accu[mi] = __builtin_amdgcn_mfma_f32_16x16x32_bf16(a, bu, accu[mi], 0, 0, 0);
          }
        }
        __builtin_amdgcn_s_setprio(0);
      }
      if (t + 1 < NT) {
        *(bf16x8*)((char*)Bs[(t+1) & 1] + wb) =
            pack8(br[(t+1) % 3][0], br[(t+1) % 3][1]);
        lds_barrier();
      }
    }

#pragma unroll
    for (int mi = 0; mi < 4; ++mi)
#pragma unroll
      for (int j = 0; j < 4; ++j) {
        int p = m0 + wm*64 + mi*16 + lk*4 + j;
        if (p < c) {
          float gv = accg[mi][j];
          float hv = (gv / (1.f + __expf(-gv))) * accu[mi][j];
          Hb[((size_t)e * TT + p) * FFN + (n0 + wn*16 + lr)] = f2bf(hv);
        }
      }
  }
}

// ---------------------------------------------------------------- GEMM2
// R17 form + T5 setprio. D=3/4-slot ring, SK=2, BN=32, NT=16,
// (e,sk)-per-XCD map, direct atomic scatter epilogue (2M atomics).
__global__ __launch_bounds__(512) void k_gemm2(
    const unsigned short* __restrict__ Hb, const float* __restrict__ down,
    const int* __restrict__ cnt, const int* __restrict__ tok,
    const float* __restrict__ wgt, float* __restrict__ out) {
  int bid = blockIdx.x;
  int xcd = bid & 7;
  int e   = xcd >> 1;
  int sk  = xcd & 1;
  int n0  = (bid >> 3) * 32;
  int c   = cnt[e];
  int kbase = sk * (FFN / SK2);           // 0 or 1024

  __shared__ alignas(16) unsigned short As[4][BM*BK];   // 4 x 32 KB
  __shared__ alignas(16) unsigned short Bs[2][32*BK];   // 2 x 4 KB

  int tid  = threadIdx.x;
  int lane = tid & 63, wv = tid >> 6;     // 8 waves
  int lr = lane & 15,  lk = lane >> 4;
  int wm = wv >> 1,    wn = wv & 1;       // 4M x 2N

  const unsigned short* Ab = Hb   + (size_t)e * TT * FFN + kbase;
  const float*          Db = down + (size_t)e * HH * FFN;

  int arow[4], acol[4], dstA[4];
#pragma unroll
  for (int cc = 0; cc < 4; ++cc) {
    int chunk = wv * 4 + cc;
    int P = chunk * 1024 + lane * 16;
    arow[cc] = P >> 7;
    acol[cc] = (P & 127) ^ ((arow[cc] & 7) << 4);
    dstA[cc] = P;
  }

  int rb  = tid >> 4;                     // 0..31
  int cbf = (tid & 15) * 4;
  const float* gB = Db + (size_t)(n0 + rb) * FFN + kbase + cbf;
  int wb = swz(rb * 128 + cbf * 2);

  int aoff[4][2], boff[2];
#pragma unroll
  for (int mi = 0; mi < 4; ++mi)
#pragma unroll
    for (int kk = 0; kk < 2; ++kk)
      aoff[mi][kk] = swz((wm*64 + mi*16 + lr) * 128 + kk*64 + lk*16);
#pragma unroll
  for (int kk = 0; kk < 2; ++kk)
    boff[kk] = swz((wn*16 + lr) * 128 + kk*64 + lk*16);

  const int NT = (FFN / SK2) / BK;   // 16

  for (int m0 = 0; m0 < c; m0 += BM) {
    __syncthreads();

    const char* srcA[4];
#pragma unroll
    for (int cc = 0; cc < 4; ++cc)
      srcA[cc] = (const char*)(Ab + (size_t)(m0 + arow[cc]) * FFN) + acol[cc];

    f32x4 acc[4];
    f32x4 z = {0.f, 0.f, 0.f, 0.f};
#pragma unroll
    for (int a = 0; a < 4; ++a) acc[a] = z;

    f32x4 br[3];

    br[0] = *(const f32x4*)(gB);
#pragma unroll
    for (int cc = 0; cc < 4; ++cc) async16((char*)As[0] + dstA[cc], srcA[cc]);
#pragma unroll
    for (int cc = 0; cc < 4; ++cc) async16((char*)As[1] + dstA[cc], srcA[cc] + BK*2);
#pragma unroll
    for (int cc = 0; cc < 4; ++cc) async16((char*)As[2] + dstA[cc], srcA[cc] + 2*BK*2);
    br[1] = *(const f32x4*)(gB + BK);
    br[2] = *(const f32x4*)(gB + 2*BK);
    *(u16x4*)((char*)Bs[0] + wb) = pack4(br[0]);
    asm volatile("s_waitcnt vmcnt(10)" ::: "memory");
    lds_barrier();

#pragma unroll
    for (int t = 0; t < NT; ++t) {
      if (t + 3 < NT) {
        int k3 = (t + 3) * BK;
#pragma unroll
        for (int cc = 0; cc < 4; ++cc)
          async16((char*)As[(t+3) & 3] + dstA[cc], srcA[cc] + k3*2);
        br[(t+3) % 3] = *(const f32x4*)(gB + k3);
      }
      __builtin_amdgcn_sched_barrier(0);
      {
        const char* Asc = (const char*)As[t & 3];
        const char* Bsc = (const char*)Bs[t & 1];
        __builtin_amdgcn_s_setprio(1);
#pragma unroll
        for (int kk = 0; kk < 2; ++kk) {
          bf16x8 bf_ = *(const bf16x8*)(Bsc + boff[kk]);
#pragma unroll
          for (int mi = 0; mi < 4; ++mi) {
            bf16x8 a = *(const bf16x8*)(Asc + aoff[mi][kk]);
            acc[mi] = __builtin_amdgcn_mfma_f32_16x16x32_bf16(a, bf_, acc[mi], 0, 0, 0);
          }
        }
        __builtin_amdgcn_s_setprio(0);
      }
      if (t + 1 < NT) {
        *(u16x4*)((char*)Bs[(t+1) & 1] + wb) = pack4(br[(t+1) % 3]);
        lds_barrier();
      }
    }

    // epilogue: direct scaled atomic scatter into out
#pragma unroll
    for (int mi = 0; mi < 4; ++mi)
#pragma unroll
      for (int j = 0; j < 4; ++j) {
        int p = m0 + wm*64 + mi*16 + lk*4 + j;
        if (p < c) {
          int   t = tok[e*TT + p];
          float w = wgt[e*TT + p];
          atomicAdd(&out[(size_t)t * HH + (n0 + wn*16 + lr)], w * acc[mi][j]);
        }
      }
  }
}

// ---------------------------------------------------------------- launch
extern "C" void kernel_launch(void* const* d_in, const int* in_sizes, int n_in,
                              void* d_out, int out_size, void* d_ws, size_t ws_size,
                              hipStream_t stream) {
  const float* hidden = (const float*)d_in[0];
  const int*   sel    = (const int*)d_in[1];
  const float* rw     = (const float*)d_in[2];
  const float* gup    = (const float*)d_in[3];
  const float* dwn    = (const float*)d_in[4];
  float* out = (float*)d_out;

  char* ws = (char*)d_ws;
  int*            cnt  = (int*)ws;                          // 1 KB pad
  int*            tok  = (int*)(ws + 1024);                 // 32 KB
  float*          wgt  = (float*)(ws + 33792);              // 32 KB
  unsigned short* X    = (unsigned short*)(ws + 66560);     // 16 MB
  unsigned short* Hb   = (unsigned short*)(ws + 16843776);  // 32 MB

  k_zb    <<<2049, 256, 0, stream>>>(out, sel, rw, cnt, tok, wgt);
  k_gather<<<dim3(TT, NL), 128, 0, stream>>>(hidden, cnt, tok, X);
  k_gemm1 <<<256, 512, 0, stream>>>(X, gup, cnt, Hb);
  k_gemm2 <<<256, 512, 0, stream>>>(Hb, dwn, cnt, tok, wgt, out);
}

// Round 23
// 54.820 us; speedup vs baseline: 1.0421x; 1.0421x over previous
//
#include <hip/hip_runtime.h>
#include <cstdint>
#include <cstddef>

#define TT  2048
#define HH  1024
#define FFN 2048
#define NL  4
#define BK  64
#define BM  256
#define SK2 2            // gemm2 split-K (chunk = 1024 -> NT=16)

typedef __attribute__((ext_vector_type(8))) short bf16x8;
typedef __attribute__((ext_vector_type(4))) unsigned short u16x4;
typedef __attribute__((ext_vector_type(4))) float f32x4;

__device__ __forceinline__ unsigned short f2bf(float f) {
  unsigned u = __builtin_bit_cast(unsigned, f);
  u += 0x7FFFu + ((u >> 16) & 1u);           // RNE
  return (unsigned short)(u >> 16);
}

__device__ __forceinline__ bf16x8 pack8(f32x4 f0, f32x4 f1) {
  bf16x8 v;
  v[0] = (short)f2bf(f0[0]); v[1] = (short)f2bf(f0[1]);
  v[2] = (short)f2bf(f0[2]); v[3] = (short)f2bf(f0[3]);
  v[4] = (short)f2bf(f1[0]); v[5] = (short)f2bf(f1[1]);
  v[6] = (short)f2bf(f1[2]); v[7] = (short)f2bf(f1[3]);
  return v;
}

__device__ __forceinline__ u16x4 pack4(f32x4 f) {
  u16x4 v;
  v[0] = f2bf(f[0]); v[1] = f2bf(f[1]); v[2] = f2bf(f[2]); v[3] = f2bf(f[3]);
  return v;
}

__device__ __forceinline__ void async16(void* lds, const void* g) {
  __builtin_amdgcn_global_load_lds(
      (const __attribute__((address_space(1))) unsigned int*)g,
      (__attribute__((address_space(3))) unsigned int*)lds, 16, 0, 0);
}

// XOR swizzle inside [rows][64 bf16] (128 B rows); involution (rule 21).
__device__ __forceinline__ int swz(int b) { return b ^ (((b >> 7) & 7) << 4); }

// lgkm-only drain + raw barrier: counted global loads stay in flight (T4).
__device__ __forceinline__ void lds_barrier() {
  asm volatile("s_waitcnt lgkmcnt(0)" ::: "memory");
  __builtin_amdgcn_s_barrier();
}

// ---------------------------------------------------------------- zero + build (fused)
__global__ __launch_bounds__(256) void k_zb(
    float* __restrict__ out, const int* __restrict__ sel,
    const float* __restrict__ rw, int* __restrict__ cnt,
    int* __restrict__ tok, float* __restrict__ wgt) {
  int b = blockIdx.x;
  if (b < 2048) {
    f32x4 z = {0.f, 0.f, 0.f, 0.f};
    reinterpret_cast<f32x4*>(out + (size_t)b * HH)[threadIdx.x] = z;
    return;
  }
  // build block (single block, LDS-atomic compaction)
  __shared__ int lcnt[NL];
  int tid = threadIdx.x;
  if (tid < NL) lcnt[tid] = 0;
  __syncthreads();
#pragma unroll
  for (int r = 0; r < TT / 256; ++r) {
    int t = r * 256 + tid;
    int   s0 = sel[t*4+0], s1 = sel[t*4+1], s2 = sel[t*4+2], s3 = sel[t*4+3];
    float r0 = rw[t*4+0],  r1 = rw[t*4+1],  r2 = rw[t*4+2],  r3 = rw[t*4+3];
#pragma unroll
    for (int i = 0; i < NL; ++i) {
      int eid = i * 8;
      float w = 0.f; bool m = false;
      if (s0 == eid) { w += r0; m = true; }
      if (s1 == eid) { w += r1; m = true; }
      if (s2 == eid) { w += r2; m = true; }
      if (s3 == eid) { w += r3; m = true; }
      if (m) {
        int p = atomicAdd(&lcnt[i], 1);
        tok[i*TT + p] = t;
        wgt[i*TT + p] = w;
      }
    }
  }
  __syncthreads();
  if (tid < NL) cnt[tid] = lcnt[tid];
}

// ---------------------------------------------------------------- gather
__global__ void k_gather(const float* __restrict__ hidden, const int* __restrict__ cnt,
                         const int* __restrict__ tok, unsigned short* __restrict__ X) {
  int p = blockIdx.x, e = blockIdx.y;
  if (p >= cnt[e]) return;
  int t = tok[e*TT + p];
  const f32x4* src = reinterpret_cast<const f32x4*>(hidden + (size_t)t * HH);
  f32x4 a = src[threadIdx.x*2], b = src[threadIdx.x*2 + 1];
  reinterpret_cast<bf16x8*>(X + ((size_t)e*TT + p) * HH)[threadIdx.x] = pack8(a, b);
}

// ---------------------------------------------------------------- GEMM1
// R13 pipeline (D=3 / 4-slot A ring via global_load_lds, B reg-prefetch
// dist 2 -> LDS dbuf, lgkm-only barriers). 256 blocks, 8 waves (4M x 2N).
// At its weight-stream roofline (~14 us for 64 MB gup).
__global__ __launch_bounds__(512) void k_gemm1(
    const unsigned short* __restrict__ X, const float* __restrict__ gup,
    const int* __restrict__ cnt, unsigned short* __restrict__ Hb) {
  int bid = blockIdx.x;
  int xcd = bid & 7;
  int e   = xcd >> 1;
  int idx = (bid >> 3) * 2 + (xcd & 1);   // 0..63
  int n0  = idx * 32;
  int c   = cnt[e];

  __shared__ alignas(16) unsigned short As[4][BM*BK];   // 4 x 32 KB
  __shared__ alignas(16) unsigned short Bs[2][64*BK];   // 2 x 8 KB

  int tid  = threadIdx.x;
  int lane = tid & 63, wv = tid >> 6;     // 8 waves
  int lr = lane & 15,  lk = lane >> 4;
  int wm = wv >> 1,    wn = wv & 1;       // 4M x 2N

  const unsigned short* Ab = X   + (size_t)e * TT * HH;
  const float*          Gb = gup + (size_t)e * 2 * FFN * HH;

  int arow[4], acol[4], dstA[4];
#pragma unroll
  for (int cc = 0; cc < 4; ++cc) {
    int chunk = wv * 4 + cc;
    int P = chunk * 1024 + lane * 16;
    arow[cc] = P >> 7;
    acol[cc] = (P & 127) ^ ((arow[cc] & 7) << 4);
    dstA[cc] = P;
  }

  int rb  = tid >> 3;                     // 0..63
  int cbf = (tid & 7) * 8;
  int grow = (rb < 32) ? (n0 + rb) : (FFN + n0 + rb - 32);
  const float* gB = Gb + (size_t)grow * HH + cbf;
  int wb = swz(rb * 128 + cbf * 2);

  int aoff[4][2], bgo[2], buo[2];
#pragma unroll
  for (int mi = 0; mi < 4; ++mi)
#pragma unroll
    for (int kk = 0; kk < 2; ++kk)
      aoff[mi][kk] = swz((wm*64 + mi*16 + lr) * 128 + kk*64 + lk*16);
#pragma unroll
  for (int kk = 0; kk < 2; ++kk) {
    bgo[kk] = swz((wn*16 + lr) * 128 + kk*64 + lk*16);
    buo[kk] = swz((32 + wn*16 + lr) * 128 + kk*64 + lk*16);
  }

  const int NT = HH / BK;   // 16

  for (int m0 = 0; m0 < c; m0 += BM) {
    __syncthreads();

    const char* srcA[4];
#pragma unroll
    for (int cc = 0; cc < 4; ++cc)
      srcA[cc] = (const char*)(Ab + (size_t)(m0 + arow[cc]) * HH) + acol[cc];

    f32x4 accg[4], accu[4];
    f32x4 z = {0.f, 0.f, 0.f, 0.f};
#pragma unroll
    for (int a = 0; a < 4; ++a) { accg[a] = z; accu[a] = z; }

    f32x4 br[3][2];

    br[0][0] = *(const f32x4*)(gB);
    br[0][1] = *(const f32x4*)(gB + 4);
#pragma unroll
    for (int cc = 0; cc < 4; ++cc) async16((char*)As[0] + dstA[cc], srcA[cc]);
#pragma unroll
    for (int cc = 0; cc < 4; ++cc) async16((char*)As[1] + dstA[cc], srcA[cc] + BK*2);
#pragma unroll
    for (int cc = 0; cc < 4; ++cc) async16((char*)As[2] + dstA[cc], srcA[cc] + 2*BK*2);
    br[1][0] = *(const f32x4*)(gB + BK);
    br[1][1] = *(const f32x4*)(gB + BK + 4);
    br[2][0] = *(const f32x4*)(gB + 2*BK);
    br[2][1] = *(const f32x4*)(gB + 2*BK + 4);
    *(bf16x8*)((char*)Bs[0] + wb) = pack8(br[0][0], br[0][1]);
    asm volatile("s_waitcnt vmcnt(12)" ::: "memory");
    lds_barrier();

#pragma unroll
    for (int t = 0; t < NT; ++t) {
      if (t + 3 < NT) {
        int k3 = (t + 3) * BK;
#pragma unroll
        for (int cc = 0; cc < 4; ++cc)
          async16((char*)As[(t+3) & 3] + dstA[cc], srcA[cc] + k3*2);
        br[(t+3) % 3][0] = *(const f32x4*)(gB + k3);
        br[(t+3) % 3][1] = *(const f32x4*)(gB + k3 + 4);
      }
      __builtin_amdgcn_sched_barrier(0);
      {
        const char* Asc = (const char*)As[t & 3];
        const char* Bsc = (const char*)Bs[t & 1];
#pragma unroll
        for (int kk = 0; kk < 2; ++kk) {
          bf16x8 bg = *(const bf16x8*)(Bsc + bgo[kk]);
          bf16x8 bu = *(const bf16x8*)(Bsc + buo[kk]);
#pragma unroll
          for (int mi = 0; mi < 4; ++mi) {
            bf16x8 a = *(const bf16x8*)(Asc + aoff[mi][kk]);
            accg[mi] = __builtin_amdgcn_mfma_f32_16x16x32_bf16(a, bg, accg[mi], 0, 0, 0);
            accu[mi] = __builtin_amdgcn_mfma_f32_16x16x32_bf16(a, bu, accu[mi], 0, 0, 0);
          }
        }
      }
      if (t + 1 < NT) {
        *(bf16x8*)((char*)Bs[(t+1) & 1] + wb) =
            pack8(br[(t+1) % 3][0], br[(t+1) % 3][1]);
        lds_barrier();
      }
    }

#pragma unroll
    for (int mi = 0; mi < 4; ++mi)
#pragma unroll
      for (int j = 0; j < 4; ++j) {
        int p = m0 + wm*64 + mi*16 + lk*4 + j;
        if (p < c) {
          float gv = accg[mi][j];
          float hv = (gv / (1.f + __expf(-gv))) * accu[mi][j];
          Hb[((size_t)e * TT + p) * FFN + (n0 + wn*16 + lr)] = f2bf(hv);
        }
      }
  }
}

// ---------------------------------------------------------------- GEMM2
// R17 form (best measured): D=3/4-slot ring, SK=2, BN=32, NT=16,
// (e,sk)-per-XCD map, direct atomic scatter epilogue (2M atomics).
__global__ __launch_bounds__(512) void k_gemm2(
    const unsigned short* __restrict__ Hb, const float* __restrict__ down,
    const int* __restrict__ cnt, const int* __restrict__ tok,
    const float* __restrict__ wgt, float* __restrict__ out) {
  int bid = blockIdx.x;
  int xcd = bid & 7;
  int e   = xcd >> 1;
  int sk  = xcd & 1;
  int n0  = (bid >> 3) * 32;
  int c   = cnt[e];
  int kbase = sk * (FFN / SK2);           // 0 or 1024

  __shared__ alignas(16) unsigned short As[4][BM*BK];   // 4 x 32 KB
  __shared__ alignas(16) unsigned short Bs[2][32*BK];   // 2 x 4 KB

  int tid  = threadIdx.x;
  int lane = tid & 63, wv = tid >> 6;     // 8 waves
  int lr = lane & 15,  lk = lane >> 4;
  int wm = wv >> 1,    wn = wv & 1;       // 4M x 2N

  const unsigned short* Ab = Hb   + (size_t)e * TT * FFN + kbase;
  const float*          Db = down + (size_t)e * HH * FFN;

  int arow[4], acol[4], dstA[4];
#pragma unroll
  for (int cc = 0; cc < 4; ++cc) {
    int chunk = wv * 4 + cc;
    int P = chunk * 1024 + lane * 16;
    arow[cc] = P >> 7;
    acol[cc] = (P & 127) ^ ((arow[cc] & 7) << 4);
    dstA[cc] = P;
  }

  int rb  = tid >> 4;                     // 0..31
  int cbf = (tid & 15) * 4;
  const float* gB = Db + (size_t)(n0 + rb) * FFN + kbase + cbf;
  int wb = swz(rb * 128 + cbf * 2);

  int aoff[4][2], boff[2];
#pragma unroll
  for (int mi = 0; mi < 4; ++mi)
#pragma unroll
    for (int kk = 0; kk < 2; ++kk)
      aoff[mi][kk] = swz((wm*64 + mi*16 + lr) * 128 + kk*64 + lk*16);
#pragma unroll
  for (int kk = 0; kk < 2; ++kk)
    boff[kk] = swz((wn*16 + lr) * 128 + kk*64 + lk*16);

  const int NT = (FFN / SK2) / BK;   // 16

  for (int m0 = 0; m0 < c; m0 += BM) {
    __syncthreads();

    const char* srcA[4];
#pragma unroll
    for (int cc = 0; cc < 4; ++cc)
      srcA[cc] = (const char*)(Ab + (size_t)(m0 + arow[cc]) * FFN) + acol[cc];

    f32x4 acc[4];
    f32x4 z = {0.f, 0.f, 0.f, 0.f};
#pragma unroll
    for (int a = 0; a < 4; ++a) acc[a] = z;

    f32x4 br[3];

    br[0] = *(const f32x4*)(gB);
#pragma unroll
    for (int cc = 0; cc < 4; ++cc) async16((char*)As[0] + dstA[cc], srcA[cc]);
#pragma unroll
    for (int cc = 0; cc < 4; ++cc) async16((char*)As[1] + dstA[cc], srcA[cc] + BK*2);
#pragma unroll
    for (int cc = 0; cc < 4; ++cc) async16((char*)As[2] + dstA[cc], srcA[cc] + 2*BK*2);
    br[1] = *(const f32x4*)(gB + BK);
    br[2] = *(const f32x4*)(gB + 2*BK);
    *(u16x4*)((char*)Bs[0] + wb) = pack4(br[0]);
    asm volatile("s_waitcnt vmcnt(10)" ::: "memory");
    lds_barrier();

#pragma unroll
    for (int t = 0; t < NT; ++t) {
      if (t + 3 < NT) {
        int k3 = (t + 3) * BK;
#pragma unroll
        for (int cc = 0; cc < 4; ++cc)
          async16((char*)As[(t+3) & 3] + dstA[cc], srcA[cc] + k3*2);
        br[(t+3) % 3] = *(const f32x4*)(gB + k3);
      }
      __builtin_amdgcn_sched_barrier(0);
      {
        const char* Asc = (const char*)As[t & 3];
        const char* Bsc = (const char*)Bs[t & 1];
#pragma unroll
        for (int kk = 0; kk < 2; ++kk) {
          bf16x8 bf_ = *(const bf16x8*)(Bsc + boff[kk]);
#pragma unroll
          for (int mi = 0; mi < 4; ++mi) {
            bf16x8 a = *(const bf16x8*)(Asc + aoff[mi][kk]);
            acc[mi] = __builtin_amdgcn_mfma_f32_16x16x32_bf16(a, bf_, acc[mi], 0, 0, 0);
          }
        }
      }
      if (t + 1 < NT) {
        *(u16x4*)((char*)Bs[(t+1) & 1] + wb) = pack4(br[(t+1) % 3]);
        lds_barrier();
      }
    }

    // epilogue: direct scaled atomic scatter into out
#pragma unroll
    for (int mi = 0; mi < 4; ++mi)
#pragma unroll
      for (int j = 0; j < 4; ++j) {
        int p = m0 + wm*64 + mi*16 + lk*4 + j;
        if (p < c) {
          int   t = tok[e*TT + p];
          float w = wgt[e*TT + p];
          atomicAdd(&out[(size_t)t * HH + (n0 + wn*16 + lr)], w * acc[mi][j]);
        }
      }
  }
}

// ---------------------------------------------------------------- launch
extern "C" void kernel_launch(void* const* d_in, const int* in_sizes, int n_in,
                              void* d_out, int out_size, void* d_ws, size_t ws_size,
                              hipStream_t stream) {
  const float* hidden = (const float*)d_in[0];
  const int*   sel    = (const int*)d_in[1];
  const float* rw     = (const float*)d_in[2];
  const float* gup    = (const float*)d_in[3];
  const float* dwn    = (const float*)d_in[4];
  float* out = (float*)d_out;

  char* ws = (char*)d_ws;
  int*            cnt  = (int*)ws;                          // 1 KB pad
  int*            tok  = (int*)(ws + 1024);                 // 32 KB
  float*          wgt  = (float*)(ws + 33792);              // 32 KB
  unsigned short* X    = (unsigned short*)(ws + 66560);     // 16 MB
  unsigned short* Hb   = (unsigned short*)(ws + 16843776);  // 32 MB

  k_zb    <<<2049, 256, 0, stream>>>(out, sel, rw, cnt, tok, wgt);
  k_gather<<<dim3(TT, NL), 128, 0, stream>>>(hidden, cnt, tok, X);
  k_gemm1 <<<256, 512, 0, stream>>>(X, gup, cnt, Hb);
  k_gemm2 <<<256, 512, 0, stream>>>(Hb, dwn, cnt, tok, wgt, out);
}